// Round 2
// baseline (251112.476 us; speedup 1.0000x reference)
//
#include <hip/hip_runtime.h>
#include <cmath>

#define BDIM 64
#define TLEN 512
#define IDIM 512
#define HDIM 1024
#define ODIM 512
#define NBLK 256
#define NTHR 512
#define KC   128

__device__ __forceinline__ float sigmoidf_(float x){ return 1.f/(1.f+__expf(-x)); }
__device__ __forceinline__ float dot4_(float4 a, float4 b){
    return a.x*b.x + a.y*b.y + a.z*b.z + a.w*b.w;
}

__global__ void gru_init(float* __restrict__ h0b, float* __restrict__ h1b,
                         int* __restrict__ ctrl)
{
    int idx = blockIdx.x * blockDim.x + threadIdx.x;
    if (idx < 2*BDIM*HDIM) { h0b[idx] = 0.f; h1b[idx] = 0.f; }
    if (idx < 2) ctrl[idx] = 0;
}

// Persistent 2-layer GRU. 256 blocks x 512 threads, 1 block/CU.
// Per block: 4 gate-columns j per layer (j = bk*4 + (wave&3)), k split across
// wave halves (kh = wave>>2), LDS reduction. Out-proj (2 rows/block) folded
// into Phase B using the waves idle in the other k-half. Grid barrier =
// device-scope atomic counter + generation spin (round-1-validated fences).
__global__ __launch_bounds__(NTHR, 2)
void gru_persist(const float* __restrict__ src,
                 const float* __restrict__ Wih0, const float* __restrict__ Whh0,
                 const float* __restrict__ bih0, const float* __restrict__ bhh0,
                 const float* __restrict__ Wih1, const float* __restrict__ Whh1,
                 const float* __restrict__ bih1, const float* __restrict__ bhh1,
                 const float* __restrict__ Wout, const float* __restrict__ bout,
                 float* __restrict__ out,
                 float* __restrict__ h0b, float* __restrict__ h1b,
                 int* __restrict__ ctrl)
{
    // 2 x 32KB staging buffers; reduction scratch aliases buf0 (every phase's
    // last compute chunk is odd -> buf1, so buf0 is dead at reduction time).
    __shared__ float sh[2*64*KC];
    float* const redL = sh;          // [4 jl][2 kh][4 v][64 b] = 2048 floats
    float* const redO = sh + 2048;   // [2 row][4 q][64 b]      = 512 floats

    const int tid  = threadIdx.x;
    const int lane = tid & 63;
    const int wave = __builtin_amdgcn_readfirstlane(tid >> 6);
    const int bk   = blockIdx.x;
    const int jl   = wave & 3;
    const int kh   = wave >> 2;
    const int swl  = lane & 31;
    const int j    = bk*4 + jl;
    int* const cnt = ctrl;
    int* const gen = ctrl + 1;

    auto stage = [&](int buf, const float* __restrict__ p, int stride, int off){
        float* dst = sh + buf*(64*KC);
        #pragma unroll
        for (int l = 0; l < (64*KC)/NTHR; ++l) {
            int idx = tid + l*NTHR;
            int bb  = idx >> 7;
            int kk  = idx & (KC-1);
            dst[bb*KC + ((((kk>>2) ^ (bb&31))<<2) | (kk&3))] = p[bb*stride + off + kk];
        }
    };
    auto ld4 = [&](int buf, int k4) -> float4 {
        return *(const float4*)&sh[buf*(64*KC) + lane*KC + (((k4>>2) ^ swl)<<2)];
    };
    auto barrier = [&](){
        __threadfence();
        __syncthreads();
        if (tid == 0) {
            int g = __hip_atomic_load(gen, __ATOMIC_RELAXED, __HIP_MEMORY_SCOPE_AGENT);
            int old = __hip_atomic_fetch_add(cnt, 1, __ATOMIC_ACQ_REL, __HIP_MEMORY_SCOPE_AGENT);
            if (old == NBLK-1) {
                __hip_atomic_store(cnt, 0, __ATOMIC_RELAXED, __HIP_MEMORY_SCOPE_AGENT);
                __hip_atomic_fetch_add(gen, 1, __ATOMIC_RELEASE, __HIP_MEMORY_SCOPE_AGENT);
            } else {
                while (__hip_atomic_load(gen, __ATOMIC_ACQUIRE, __HIP_MEMORY_SCOPE_AGENT) == g)
                    __builtin_amdgcn_s_sleep(2);
            }
        }
        __syncthreads();
        __threadfence();
    };

    for (int t = 0; t < TLEN; ++t) {
        const int rd = t & 1, wr = rd ^ 1;
        const float* h0r = h0b + rd*BDIM*HDIM;
        float*       h0w = h0b + wr*BDIM*HDIM;
        const float* h1r = h1b + rd*BDIM*HDIM;
        float*       h1w = h1b + wr*BDIM*HDIM;
        const float* xs  = src + t*IDIM;      // + b*T*I

        // ---------- Phase A: layer-0 gates (k = [x(512) | h0(1024)]) ----------
        float ar=0.f, az=0.f, anx=0.f, anh=0.f;
        __syncthreads();
        stage(0, xs, TLEN*IDIM, 0);
        for (int c = 0; c < 12; ++c) {
            __syncthreads();
            if (c+1 < 12) {
                if (c+1 < 4) stage((c+1)&1, xs, TLEN*IDIM, (c+1)*KC);
                else         stage((c+1)&1, h0r, HDIM, (c+1)*KC - IDIM);
            }
            if (c/6 == kh) {          // chunks 0-5 -> kh0, 6-11 -> kh1
                const float* Wb; int st, ko;
                if (c < 4) { Wb = Wih0; st = IDIM; ko = c*KC; }
                else       { Wb = Whh0; st = HDIM; ko = c*KC - IDIM; }
                const float* pr = Wb + (size_t)j*st + ko;
                const float* pz = Wb + (size_t)(HDIM+j)*st + ko;
                const float* pn = Wb + (size_t)(2*HDIM+j)*st + ko;
                float an_ = 0.f;
                #pragma unroll 4
                for (int k4 = 0; k4 < KC; k4 += 4) {
                    float4 v = ld4(c&1, k4);
                    ar  += dot4_(v, *(const float4*)(pr + k4));
                    az  += dot4_(v, *(const float4*)(pz + k4));
                    an_ += dot4_(v, *(const float4*)(pn + k4));
                }
                if (c < 4) anx += an_; else anh += an_;
            }
        }
        {
            float* rL = redL + (jl*2 + kh)*256;
            rL[0*64+lane]=ar; rL[1*64+lane]=az; rL[2*64+lane]=anx; rL[3*64+lane]=anh;
        }
        __syncthreads();
        if (wave < 4) {
            const int j2 = bk*4 + wave;
            const float* a0 = redL + (wave*2+0)*256;
            const float* a1 = redL + (wave*2+1)*256;
            float r  = a0[0*64+lane] + a1[0*64+lane];
            float z  = a0[1*64+lane] + a1[1*64+lane];
            float nx = a0[2*64+lane] + a1[2*64+lane];
            float nh = a0[3*64+lane] + a1[3*64+lane];
            r = sigmoidf_(r + bih0[j2] + bhh0[j2]);
            z = sigmoidf_(z + bih0[HDIM+j2] + bhh0[HDIM+j2]);
            float n = tanhf(nx + bih0[2*HDIM+j2] + r*(nh + bhh0[2*HDIM+j2]));
            h0w[lane*HDIM + j2] = (1.f - z)*n + z*h0r[lane*HDIM + j2];
        }
        barrier();

        // ------ Phase B: layer-1 gates (k = [h0new | h1prev]) + out(t-1) ------
        ar=0.f; az=0.f; anx=0.f; anh=0.f;
        float oacc = 0.f;
        __syncthreads();
        stage(0, h0w, HDIM, 0);
        for (int c = 0; c < 16; ++c) {
            __syncthreads();
            if (c+1 < 16) {
                if (c+1 < 8) stage((c+1)&1, h0w, HDIM, (c+1)*KC);
                else         stage((c+1)&1, h1r, HDIM, (c+1)*KC - HDIM);
            }
            if (c/8 == kh) {          // chunks 0-7 -> kh0 (Wih1), 8-15 -> kh1 (Whh1)
                const float* Wb; int ko;
                if (c < 8) { Wb = Wih1; ko = c*KC; }
                else       { Wb = Whh1; ko = c*KC - HDIM; }
                const float* pr = Wb + (size_t)j*HDIM + ko;
                const float* pz = Wb + (size_t)(HDIM+j)*HDIM + ko;
                const float* pn = Wb + (size_t)(2*HDIM+j)*HDIM + ko;
                float an_ = 0.f;
                #pragma unroll 4
                for (int k4 = 0; k4 < KC; k4 += 4) {
                    float4 v = ld4(c&1, k4);
                    ar  += dot4_(v, *(const float4*)(pr + k4));
                    az  += dot4_(v, *(const float4*)(pz + k4));
                    an_ += dot4_(v, *(const float4*)(pn + k4));
                }
                if (c < 8) anx += an_; else anh += an_;
            } else if (kh == 0 && c >= 8 && t > 0) {
                // waves 0-3 idle for L1 here: out(t-1) from staged h1r chunks
                if (((c-8)>>2) == (wave>>1)) {
                    const int o = bk*2 + (wave&1);
                    const float* po = Wout + (size_t)o*HDIM + (c-8)*KC;
                    #pragma unroll 4
                    for (int k4 = 0; k4 < KC; k4 += 4)
                        oacc += dot4_(ld4(c&1, k4), *(const float4*)(po + k4));
                }
            }
        }
        {
            float* rL = redL + (jl*2 + kh)*256;
            rL[0*64+lane]=ar; rL[1*64+lane]=az; rL[2*64+lane]=anx; rL[3*64+lane]=anh;
            if (wave < 4 && t > 0)
                redO[(wave&1)*256 + (wave>>1)*64 + lane] = oacc;
        }
        __syncthreads();
        if (wave < 4) {
            const int j2 = bk*4 + wave;
            const float* a0 = redL + (wave*2+0)*256;
            const float* a1 = redL + (wave*2+1)*256;
            float r  = a0[0*64+lane] + a1[0*64+lane];
            float z  = a0[1*64+lane] + a1[1*64+lane];
            float nx = a0[2*64+lane] + a1[2*64+lane];
            float nh = a0[3*64+lane] + a1[3*64+lane];
            r = sigmoidf_(r + bih1[j2] + bhh1[j2]);
            z = sigmoidf_(z + bih1[HDIM+j2] + bhh1[HDIM+j2]);
            float n = tanhf(nx + bih1[2*HDIM+j2] + r*(nh + bhh1[2*HDIM+j2]));
            h1w[lane*HDIM + j2] = (1.f - z)*n + z*h1r[lane*HDIM + j2];
        } else if (wave < 6 && t > 0) {
            const int row = wave - 4, o = bk*2 + row;
            float v = redO[row*256 + lane] + redO[row*256 + 64 + lane] + bout[o];
            out[(size_t)(t-1)*BDIM*ODIM + lane*ODIM + o] = v;
        }
        barrier();
    }

    // ---------------- epilogue: out(T-1) from final h1 (buffer 0) -------------
    {
        const float* h1f = h1b;                 // wr at t=511 is buffer 0
        const int row = wave & 1, q = wave >> 1;
        const int o = bk*2 + row;
        float oa = 0.f;
        __syncthreads();
        stage(0, h1f, HDIM, 0);
        for (int c = 0; c < 8; ++c) {
            __syncthreads();
            if (c+1 < 8) stage((c+1)&1, h1f, HDIM, (c+1)*KC);
            if ((c>>1) == q) {
                const float* po = Wout + (size_t)o*HDIM + c*KC;
                #pragma unroll 4
                for (int k4 = 0; k4 < KC; k4 += 4)
                    oa += dot4_(ld4(c&1, k4), *(const float4*)(po + k4));
            }
        }
        redO[row*256 + q*64 + lane] = oa;
        __syncthreads();
        if (wave < 2) {
            const int o2 = bk*2 + wave;
            float v = bout[o2];
            #pragma unroll
            for (int qq = 0; qq < 4; ++qq) v += redO[wave*256 + qq*64 + lane];
            out[(size_t)(TLEN-1)*BDIM*ODIM + lane*ODIM + o2] = v;
        }
    }
}

extern "C" void kernel_launch(void* const* d_in, const int* in_sizes, int n_in,
                              void* d_out, int out_size, void* d_ws, size_t ws_size,
                              hipStream_t stream)
{
    const float* src  = (const float*)d_in[0];
    // d_in[1] = target, unused
    const float* Wih0 = (const float*)d_in[2];
    const float* Whh0 = (const float*)d_in[3];
    const float* bih0 = (const float*)d_in[4];
    const float* bhh0 = (const float*)d_in[5];
    const float* Wih1 = (const float*)d_in[6];
    const float* Whh1 = (const float*)d_in[7];
    const float* bih1 = (const float*)d_in[8];
    const float* bhh1 = (const float*)d_in[9];
    const float* Wout = (const float*)d_in[10];
    const float* bout = (const float*)d_in[11];
    float* out = (float*)d_out;

    // ws: h0 double buffer | h1 double buffer | ctrl(cnt, gen)
    float* ws  = (float*)d_ws;
    float* h0b = ws;
    float* h1b = ws + 2*BDIM*HDIM;
    int*   ctrl = (int*)(ws + 4*BDIM*HDIM);

    hipLaunchKernelGGL(gru_init, dim3(NBLK), dim3(NTHR), 0, stream, h0b, h1b, ctrl);
    hipLaunchKernelGGL(gru_persist, dim3(NBLK), dim3(NTHR), 0, stream,
                       src, Wih0, Whh0, bih0, bhh0, Wih1, Whh1, bih1, bhh1,
                       Wout, bout, out, h0b, h1b, ctrl);
}

// Round 3
// 63510.504 us; speedup vs baseline: 3.9539x; 3.9539x over previous
//
#include <hip/hip_runtime.h>
#include <hip/hip_fp16.h>
#include <cmath>

#define BDIM 64
#define TLEN 512
#define IDIM 512
#define HDIM 1024
#define ODIM 512
#define NBLK 256
#define NTHR 512

typedef _Float16 h16;
typedef _Float16 half8 __attribute__((ext_vector_type(8)));
typedef float f32x4 __attribute__((ext_vector_type(4)));

__device__ __forceinline__ float sigf(float x){ return 1.f/(1.f+__expf(-x)); }

// Activation planes (per layer): [slot 2][pl 2 (hi/lo)][bt 4][k8 32][lane 64][8] fp16.
// B-fragment-ready for mfma_f32_16x16x32_f16: element (k8, L, j) = act[b = bt*16 + (L&15)]
// [k = k8*32 + (L>>4)*8 + j].
#define PLANE_ELEMS (2*2*4*32*64*8)   // 262144 h16 per layer (512 KB)
__device__ __forceinline__ size_t poff(int slot,int pl,int bt,int k8){
    return ((((size_t)slot*2+pl)*4+bt)*32 + (size_t)k8)*512;
}

__global__ void gru_init(h16* __restrict__ planes, int* __restrict__ ctrl){
    size_t n = 2*(size_t)PLANE_ELEMS;
    for (size_t i = (size_t)blockIdx.x*blockDim.x + threadIdx.x; i < n;
         i += (size_t)gridDim.x*blockDim.x)
        planes[i] = (h16)0.f;
    if (blockIdx.x==0 && threadIdx.x<2) ctrl[threadIdx.x] = 0;
}

// Persistent pipelined 2-layer GRU + out-proj. 256 blocks x 512 threads, 1/CU.
// bk<128: L0-block, owns h0 units [8bk,8bk+8). bk>=128: L1-block, owns h1 units
// [8i,8i+8) and out rows [4i,4i+4), i=bk-128.
// Weights live in LDS as fp16 A-fragments: 2 m-tiles x K8 k-chunks x 64 lanes x 8.
//   tile0 = [r(u0..7) | z(u0..7)], tile1 = [n(u0..7) | out(0..3)/zeros | zeros].
// Accs split at KS8 (x/ih-part vs h/hh-part) -> n-gate and out fall out naturally.
// Phase p: L0 computes h0(p) (p<T); L1 computes h1(p-1) (1<=p<=T) and out(p-2)
// (2<=p<=T+1). One grid barrier per phase, 514 phases.
__global__ __launch_bounds__(NTHR,1)
void gru_persist(const float* __restrict__ src,
                 const float* __restrict__ Wih0, const float* __restrict__ Whh0,
                 const float* __restrict__ bih0, const float* __restrict__ bhh0,
                 const float* __restrict__ Wih1, const float* __restrict__ Whh1,
                 const float* __restrict__ bih1, const float* __restrict__ bhh1,
                 const float* __restrict__ Wout, const float* __restrict__ bout,
                 float* __restrict__ out,
                 h16* __restrict__ h0pl, h16* __restrict__ h1pl,
                 int* __restrict__ ctrl)
{
    extern __shared__ char lds[];
    const int tid  = threadIdx.x;
    const int lane = tid & 63;
    const int wv   = __builtin_amdgcn_readfirstlane(tid >> 6);
    const int bt   = wv & 3;          // batch tile (16 b)
    const int kh2  = wv >> 2;         // k-half
    const int bk   = blockIdx.x;
    const int role = (bk >= 128);     // 0 = L0, 1 = L1
    const int ib   = role ? bk - 128 : bk;
    const int U    = 8 * ib;
    const int K8   = role ? 64 : 48;  // k8 chunks (K = 2048 / 1536)
    const int KS8  = role ? 32 : 16;  // accA/accB split (k=1024 / k=512)

    h16*   Alds = (h16*)lds;                                   // [2][K8][64][8]
    float* scr  = (float*)(lds + (size_t)2*K8*64*8*sizeof(h16)); // [4][2][2][4][64]

    int* const cnt = ctrl;
    int* const gen = ctrl + 1;

    // ---------------- prologue: fp32 weights -> fp16 A-fragments in LDS -------
    {
        const int t = tid >> 8;          // tile
        const int m = (tid >> 4) & 15;   // row within tile
        for (int k8 = (tid & 15); k8 < K8; k8 += 16) {
            for (int q = 0; q < 4; ++q) {
                half8 hv;
                #pragma unroll
                for (int j = 0; j < 8; ++j) {
                    const int c = k8*32 + q*8 + j;
                    float v;
                    if (!role) {
                        if (t == 1 && m >= 8) v = 0.f;
                        else {
                            int grow = (t==0) ? ((m<8)? U+m : HDIM+U+(m-8)) : (2*HDIM+U+m);
                            v = (c < IDIM) ? Wih0[(size_t)grow*IDIM + c]
                                           : Whh0[(size_t)grow*HDIM + (c-IDIM)];
                        }
                    } else {
                        if (t == 1 && m >= 8) {
                            if (m < 12) {
                                int o = 4*ib + (m-8);
                                v = (c < HDIM) ? 0.f : Wout[(size_t)o*HDIM + (c-HDIM)];
                            } else v = 0.f;
                        } else {
                            int grow = (t==0) ? ((m<8)? U+m : HDIM+U+(m-8)) : (2*HDIM+U+m);
                            v = (c < HDIM) ? Wih1[(size_t)grow*HDIM + c]
                                           : Whh1[(size_t)grow*HDIM + (c-HDIM)];
                        }
                    }
                    hv[j] = (h16)v;
                }
                *(half8*)&Alds[(((size_t)t*K8 + k8)*64 + q*16 + m)*8] = hv;
            }
        }
    }

    // per-thread epilogue identity: (unit eu, batch eb)
    const int eu = tid >> 6, eb = tid & 63;
    float br,bz,bnx,bnh;
    if (!role){ br = bih0[U+eu]+bhh0[U+eu]; bz = bih0[HDIM+U+eu]+bhh0[HDIM+U+eu];
                bnx = bih0[2*HDIM+U+eu];    bnh = bhh0[2*HDIM+U+eu]; }
    else      { br = bih1[U+eu]+bhh1[U+eu]; bz = bih1[HDIM+U+eu]+bhh1[HDIM+U+eu];
                bnx = bih1[2*HDIM+U+eu];    bnh = bhh1[2*HDIM+U+eu]; }
    float bo = 0.f;
    if (role && tid < 256) bo = bout[4*ib + (tid>>6)];
    float hprev = 0.f;

    __syncthreads();

    auto barrier = [&](){
        __threadfence();
        __syncthreads();
        if (tid == 0) {
            int g = __hip_atomic_load(gen, __ATOMIC_RELAXED, __HIP_MEMORY_SCOPE_AGENT);
            int old = __hip_atomic_fetch_add(cnt, 1, __ATOMIC_ACQ_REL, __HIP_MEMORY_SCOPE_AGENT);
            if (old == NBLK-1) {
                __hip_atomic_store(cnt, 0, __ATOMIC_RELAXED, __HIP_MEMORY_SCOPE_AGENT);
                __hip_atomic_fetch_add(gen, 1, __ATOMIC_RELEASE, __HIP_MEMORY_SCOPE_AGENT);
            } else {
                while (__hip_atomic_load(gen, __ATOMIC_ACQUIRE, __HIP_MEMORY_SCOPE_AGENT) == g)
                    __builtin_amdgcn_s_sleep(1);
            }
        }
        __syncthreads();
        __threadfence();
    };

    for (int p = 0; p <= TLEN+1; ++p) {
        const bool act = role ? (p >= 1) : (p < TLEN);
        if (act) {
            f32x4 acc00 = {0.f,0.f,0.f,0.f}, acc01 = {0.f,0.f,0.f,0.f};
            f32x4 acc10 = {0.f,0.f,0.f,0.f}, acc11 = {0.f,0.f,0.f,0.f};

            // B-plane base for this wave
            const h16* BH; int koff;
            if (!role)          { BH = h0pl + poff((p-1)&1,0,bt,0); koff = 16; }
            else if (kh2 == 0)  { BH = h0pl + poff((p-1)&1,0,bt,0); koff = 0;  }
            else                { BH = h1pl + poff( p   &1,0,bt,0); koff = 32; }
            const h16* BL = BH + (size_t)4*32*512 * 0 + 65536; // pl-stride = 65536 elems

            const int k8lo = kh2 * (K8/2), k8hi = k8lo + K8/2;
            #pragma unroll 4
            for (int k8 = k8lo; k8 < k8hi; ++k8) {
                half8 bh, bl;
                if (!role && k8 < 16) {
                    // x(p): fp32 global -> hi/lo fp16 B-fragment in regs
                    const float* xp = src + ((size_t)(bt*16 + (lane&15))*TLEN + p)*IDIM
                                          + k8*32 + (lane>>4)*8;
                    float4 f0 = *(const float4*)xp;
                    float4 f1 = *(const float4*)(xp+4);
                    float f[8] = {f0.x,f0.y,f0.z,f0.w,f1.x,f1.y,f1.z,f1.w};
                    #pragma unroll
                    for (int j = 0; j < 8; ++j) {
                        h16 h = (h16)f[j];
                        bh[j] = h; bl[j] = (h16)(f[j] - (float)h);
                    }
                } else {
                    size_t o = ((size_t)(k8 - koff)*64 + lane)*8;
                    bh = *(const half8*)(BH + o);
                    bl = *(const half8*)(BL + o);
                }
                half8 a0 = *(const half8*)&Alds[(((size_t)0*K8 + k8)*64 + lane)*8];
                half8 a1 = *(const half8*)&Alds[(((size_t)1*K8 + k8)*64 + lane)*8];
                if (k8 < KS8) {
                    acc00 = __builtin_amdgcn_mfma_f32_16x16x32_f16(a0, bh, acc00, 0,0,0);
                    acc00 = __builtin_amdgcn_mfma_f32_16x16x32_f16(a0, bl, acc00, 0,0,0);
                    acc10 = __builtin_amdgcn_mfma_f32_16x16x32_f16(a1, bh, acc10, 0,0,0);
                    acc10 = __builtin_amdgcn_mfma_f32_16x16x32_f16(a1, bl, acc10, 0,0,0);
                } else {
                    acc01 = __builtin_amdgcn_mfma_f32_16x16x32_f16(a0, bh, acc01, 0,0,0);
                    acc01 = __builtin_amdgcn_mfma_f32_16x16x32_f16(a0, bl, acc01, 0,0,0);
                    acc11 = __builtin_amdgcn_mfma_f32_16x16x32_f16(a1, bh, acc11, 0,0,0);
                    acc11 = __builtin_amdgcn_mfma_f32_16x16x32_f16(a1, bl, acc11, 0,0,0);
                }
            }

            // cross-wave (k-half) reduction via LDS scratch
            if (kh2 == 1) {
                #pragma unroll
                for (int r = 0; r < 4; ++r) {
                    scr[(((bt*2+0)*2+0)*4+r)*64 + lane] = acc00[r];
                    scr[(((bt*2+0)*2+1)*4+r)*64 + lane] = acc01[r];
                    scr[(((bt*2+1)*2+0)*4+r)*64 + lane] = acc10[r];
                    scr[(((bt*2+1)*2+1)*4+r)*64 + lane] = acc11[r];
                }
            }
            __syncthreads();
            if (kh2 == 0) {
                #pragma unroll
                for (int r = 0; r < 4; ++r) {
                    scr[(((bt*2+0)*2+0)*4+r)*64 + lane] += acc00[r];
                    scr[(((bt*2+0)*2+1)*4+r)*64 + lane] += acc01[r];
                    scr[(((bt*2+1)*2+0)*4+r)*64 + lane] += acc10[r];
                    scr[(((bt*2+1)*2+1)*4+r)*64 + lane] += acc11[r];
                }
            }
            __syncthreads();

            // ---- gate epilogue: thread (eu, eb) -> D rows (r: eu, z: 8+eu, n: eu) ----
            {
                const int bte = eb>>4, le = eb&15, lq = eu>>2, rr = eu&3;
                auto rdv = [&](int t,int ab,int q)->float{
                    return scr[(((bte*2+t)*2+ab)*4+rr)*64 + q*16 + le];
                };
                float rv = rdv(0,0,lq)   + rdv(0,1,lq)   + br;
                float zv = rdv(0,0,2+lq) + rdv(0,1,2+lq) + bz;
                float nx = rdv(1,0,lq) + bnx;
                float nh = rdv(1,1,lq) + bnh;
                float r = sigf(rv), z = sigf(zv);
                float n = tanhf(nx + r*nh);
                float h = (1.f - z)*n + z*hprev;
                if (!role || p <= TLEN) {
                    hprev = h;
                    h16 hh = (h16)h;
                    h16 hl = (h16)(h - (float)hh);
                    const int uu = U + eu;
                    const int slot = (!role) ? (p&1) : ((p-1)&1);
                    h16* base = (!role) ? h0pl : h1pl;
                    size_t o = poff(slot, 0, eb>>4, uu>>5)
                             + (size_t)(((uu>>3)&3)*16 + (eb&15))*8 + (uu&7);
                    base[o]         = hh;
                    base[o + 65536] = hl;   // pl-stride
                }
            }
            // ---- out(p-2): T1 accB rows 8..11 ----
            if (role && p >= 2 && tid < 256) {
                const int ro = tid >> 6, b = tid & 63;
                float v = scr[((((b>>4)*2+1)*2+1)*4 + ro)*64 + 32 + (b&15)] + bo;
                out[((size_t)(p-2)*BDIM + b)*ODIM + (4*ib + ro)] = v;
            }
        }
        barrier();
    }
}

extern "C" void kernel_launch(void* const* d_in, const int* in_sizes, int n_in,
                              void* d_out, int out_size, void* d_ws, size_t ws_size,
                              hipStream_t stream)
{
    const float* src  = (const float*)d_in[0];
    // d_in[1] = target, unused
    const float* Wih0 = (const float*)d_in[2];
    const float* Whh0 = (const float*)d_in[3];
    const float* bih0 = (const float*)d_in[4];
    const float* bhh0 = (const float*)d_in[5];
    const float* Wih1 = (const float*)d_in[6];
    const float* Whh1 = (const float*)d_in[7];
    const float* bih1 = (const float*)d_in[8];
    const float* bhh1 = (const float*)d_in[9];
    const float* Wout = (const float*)d_in[10];
    const float* bout = (const float*)d_in[11];
    float* out = (float*)d_out;

    // ws: h0 planes (512 KB) | h1 planes (512 KB) | ctrl
    h16* h0pl = (h16*)d_ws;
    h16* h1pl = h0pl + PLANE_ELEMS;
    int* ctrl = (int*)((char*)d_ws + 2*(size_t)PLANE_ELEMS*sizeof(h16));

    // L1 blocks need 128 KB weights + 16 KB scratch = 144 KB dynamic LDS
    const int ldsBytes = 2*64*64*8*2 + 4*2*2*4*64*4;   // 131072 + 16384 = 147456
    (void)hipFuncSetAttribute((const void*)gru_persist,
                              hipFuncAttributeMaxDynamicSharedMemorySize, ldsBytes);

    hipLaunchKernelGGL(gru_init, dim3(256), dim3(256), 0, stream, h0pl, ctrl);
    hipLaunchKernelGGL(gru_persist, dim3(NBLK), dim3(NTHR), ldsBytes, stream,
                       src, Wih0, Whh0, bih0, bhh0, Wih1, Whh1, bih1, bhh1,
                       Wout, bout, out, h0pl, h1pl, ctrl);
}